// Round 2
// baseline (330.382 us; speedup 1.0000x reference)
//
#include <hip/hip_runtime.h>

// Stream compaction, single-pass (R7):
//   mask[i]  = accept_index[i] >= 0
//   dst[i]   = exclusive_prefix_sum(mask)[i]
//   out[dst[i]] = out_cache_loc[accept_index[i]]  for mask[i]
//   out[total..N) = 0
//
// R6 post-mortem: fused kernel = 212us, VALUBusy 6.5%, occupancy 30%,
// FETCH 684MB (= L2-miss traffic, mostly L3-absorbed). The gather is
// latency-bound: ~90 outstanding misses/CU x 64B / ~500cy (L3 hit) matches
// the observed throughput. R7 attacks latency x concurrency:
//   - SLICE_LG 22->20: 4MB slices fit the per-XCD L2 -> gather reads become
//     ~220cy L2 hits instead of ~500cy L3 hits.
//   - EPT2 32->16: LDS 33KB->16.5KB -> ~7 blocks/CU (28 waves vs 16) ->
//     ~2x outstanding misses; VGPR drops with the smaller per-thread arrays.
// Gather core structure (branch-free batched loads, one vmcnt(0) per slice,
// LDS compact, coalesced store, fused tail-zero) unchanged from R6.

#define N_TOTAL  16777216
#define BLOCK    256

#define EPT2     16
#define TILE2    (BLOCK * EPT2)        // 4096
#define NB2      (N_TOTAL / TILE2)     // 4096

#define SLICE_LG 20                    // 2^20 elements = 4 MB per slice
#define SLICES   (N_TOTAL >> SLICE_LG) // 16

typedef float vfloat4 __attribute__((ext_vector_type(4)));

// ---------------- pass 0: zero the lookback state (32 KB) ----------------
__global__ __launch_bounds__(256) void k_init(unsigned long long* __restrict__ state) {
    state[blockIdx.x * 256 + threadIdx.x] = 0ULL;
}

// ---------------- single fused pass ----------------
__global__ __launch_bounds__(BLOCK) void k_compact(const int* __restrict__ idx,
                                                   const float* __restrict__ src,
                                                   float* __restrict__ out,
                                                   unsigned long long* __restrict__ state) {
    const int b = blockIdx.x;
    const int t = threadIdx.x;
    const int lane = t & 63, wave = t >> 6;

    // ---- load idx tile (only read of accept_index in the whole pipeline) ----
    const int4* p = (const int4*)(idx + (size_t)b * TILE2 + (size_t)t * EPT2);
    int v[EPT2];
#pragma unroll
    for (int j = 0; j < EPT2 / 4; ++j) {
        int4 q = p[j];
        v[4 * j + 0] = q.x; v[4 * j + 1] = q.y;
        v[4 * j + 2] = q.z; v[4 * j + 3] = q.w;
    }
    int cnt = 0;
#pragma unroll
    for (int j = 0; j < EPT2; ++j) cnt += (v[j] >= 0);

    // ---- block exclusive scan of per-thread counts ----
    int x = cnt;
#pragma unroll
    for (int d = 1; d < 64; d <<= 1) {
        int y = __shfl_up(x, d);
        if (lane >= d) x += y;
    }
    __shared__ int wsum[BLOCK / 64], woff[BLOCK / 64], btotal;
    __shared__ long long sBase;
    if (lane == 63) wsum[wave] = x;
    __syncthreads();
    if (t == 0) {
        int s = 0;
#pragma unroll
        for (int w = 0; w < BLOCK / 64; ++w) { woff[w] = s; s += wsum[w]; }
        btotal = s;
        if (b == 0) {
            // flag 2 = PREFIX (inclusive), value in bits [2..]
            __hip_atomic_store(&state[0], ((unsigned long long)s << 2) | 2ULL,
                               __ATOMIC_RELAXED, __HIP_MEMORY_SCOPE_AGENT);
            sBase = 0;
        } else {
            // flag 1 = PARTIAL (aggregate) -- published before the gather phase
            __hip_atomic_store(&state[b], ((unsigned long long)s << 2) | 1ULL,
                               __ATOMIC_RELAXED, __HIP_MEMORY_SCOPE_AGENT);
        }
    }

    // ---- decoupled lookback: wave 0, 64-wide windows ----
    if (b > 0 && wave == 0) {
        long long excl = 0;
        int look = b - 1;
        for (;;) {
            const int pos = look - lane;              // lane 0 = nearest predecessor
            unsigned long long s = 2ULL;              // pos<0 -> fake PREFIX(0)
            if (pos >= 0)
                s = __hip_atomic_load(&state[pos], __ATOMIC_RELAXED,
                                      __HIP_MEMORY_SCOPE_AGENT);
            for (;;) {
                const bool need = (pos >= 0) && ((s & 3ULL) == 0ULL);
                if (!__any(need)) break;
                if (need) {
                    __builtin_amdgcn_s_sleep(2);      // throttle spin traffic
                    s = __hip_atomic_load(&state[pos], __ATOMIC_RELAXED,
                                          __HIP_MEMORY_SCOPE_AGENT);
                }
            }
            const unsigned long long ball = __ballot((s & 3ULL) == 2ULL);
            const int fp = ball ? (__ffsll((long long)ball) - 1) : 64;
            long long c = (lane <= fp) ? (long long)(s >> 2) : 0; // fp==64 -> all
#pragma unroll
            for (int d = 32; d; d >>= 1) c += __shfl_down(c, d);
            excl += __shfl(c, 0);
            if (ball) break;                          // found a PREFIX -> done
            look -= 64;                               // whole window PARTIAL
        }
        if (lane == 0) {
            __hip_atomic_store(&state[b],
                               (((unsigned long long)(excl + btotal)) << 2) | 2ULL,
                               __ATOMIC_RELAXED, __HIP_MEMORY_SCOPE_AGENT);
            sBase = excl;
        }
    }
    __syncthreads();

    const int off0 = (x - cnt) + woff[wave];   // this thread's first LDS slot
    const int tot  = btotal;
    const long long base = sBase;              // global exclusive accept prefix

    // ---- slice-swept batched gather -> LDS compact ----
    // Per slice: EPT2 BRANCH-FREE loads (non-matching lanes read src[0],
    // which stays L1-hot) -> one vmcnt(0) -> conditional LDS commit. The
    // 4MB slice stays resident in each XCD's L2 across the slice window.
    __shared__ float vals[TILE2];
#pragma unroll 1
    for (int s = 0; s < SLICES; ++s) {
        float tmp[EPT2];
#pragma unroll
        for (int j = 0; j < EPT2; ++j) {
            const bool m = (int)((unsigned)v[j] >> SLICE_LG) == s;
            tmp[j] = src[m ? v[j] : 0];
        }
        asm volatile("s_waitcnt vmcnt(0)" ::: "memory");
        int o = off0;
#pragma unroll
        for (int j = 0; j < EPT2; ++j) {
            const bool acc = v[j] >= 0;
            const bool m = (int)((unsigned)v[j] >> SLICE_LG) == s;
            if (m) vals[o] = tmp[j];
            o += acc;
        }
    }
    __syncthreads();

    // ---- contiguous, fully-coalesced block write: [base, base+tot) ----
    for (int i = t; i < tot; i += BLOCK)
        __builtin_nontemporal_store(vals[i], out + base + i);

    // ---- fused tail zero via reject-prefix identity ----
    // rejects before this block: r_b = b*TILE2 - base; this block owes
    // rcnt = TILE2 - tot zeros at [N - r_b - rcnt, N - r_b). Union over all
    // blocks = [total, N), disjoint, never overlaps data writes.
    const long long rprev = (long long)b * TILE2 - base;
    const int rcnt = TILE2 - tot;
    float* zp = out + ((long long)N_TOTAL - rprev - rcnt);
    for (int i = t; i < rcnt; i += BLOCK)
        __builtin_nontemporal_store(0.0f, zp + i);
}

extern "C" void kernel_launch(void* const* d_in, const int* in_sizes, int n_in,
                              void* d_out, int out_size, void* d_ws, size_t ws_size,
                              hipStream_t stream) {
    const int*   idx = (const int*)d_in[0];     // accept_index (int32 per harness)
    const float* src = (const float*)d_in[1];   // out_cache_loc
    float*       out = (float*)d_out;

    unsigned long long* state = (unsigned long long*)d_ws;  // NB2 x u64 = 32 KB

    k_init   <<<NB2 / 256, 256, 0, stream>>>(state);
    k_compact<<<NB2, BLOCK, 0, stream>>>(idx, src, out, state);
}

// Round 4
// 328.286 us; speedup vs baseline: 1.0064x; 1.0064x over previous
//
#include <hip/hip_runtime.h>

// Stream compaction, single-pass persistent (R9 = R8 + compile fix):
//   mask[i]  = accept_index[i] >= 0
//   dst[i]   = exclusive_prefix_sum(mask)[i]
//   out[dst[i]] = out_cache_loc[accept_index[i]]  for mask[i]
//   out[total..N) = 0
//
// R7 post-mortem: occupancy 2x, latency path shortened -> NO change in dur or
// FETCH (698MB vs 576MB floor = 8 XCD x 64MB src + 64MB idx). Not
// concurrency-bound. L2 residency never materialized because (a) grid 4096 >
// resident 2048 -> two generations sweep different slices simultaneously,
// (b) slice == L2 size exactly, (c) ~120MB excess fetch tracks output size ->
// store RFO. R8/R9:
//   - persistent 2048 blocks (exactly 8/CU, pinned via __launch_bounds__),
//     2 tiles each -> all blocks in-phase -> slice genuinely L2-resident.
//   - lookback moved AFTER the gather sweep (off critical path; predecessors
//     are published by then).
//   - float4 NT stores with alignment peel (data + tail zero) -> kill RFO.
//   - NT idx loads via ext_vector int4 (HIP int4 rejected by the builtin).
// Gather core (branch-free batched loads, one vmcnt(0) per slice, LDS
// compact, coalesced store, fused tail-zero identity) unchanged.

#define N_TOTAL  16777216
#define BLOCK    256

#define EPT2     16
#define TILE2    (BLOCK * EPT2)        // 4096
#define NB2      (N_TOTAL / TILE2)     // 4096 tiles
#define GRID     2048                  // persistent blocks (8/CU x 256 CU)
#define GENS     (NB2 / GRID)          // 2 tiles per block

#define SLICE_LG 20                    // 2^20 elements = 4 MB per slice
#define SLICES   (N_TOTAL >> SLICE_LG) // 16

typedef float vfloat4 __attribute__((ext_vector_type(4)));
typedef int   vint4   __attribute__((ext_vector_type(4)));

// ---------------- pass 0: zero the lookback state (32 KB) ----------------
__global__ __launch_bounds__(256) void k_init(unsigned long long* __restrict__ state) {
    state[blockIdx.x * 256 + threadIdx.x] = 0ULL;
}

// ---------------- single fused persistent pass ----------------
__global__ __launch_bounds__(BLOCK, 8) void k_compact(const int* __restrict__ idx,
                                                      const float* __restrict__ src,
                                                      float* __restrict__ out,
                                                      unsigned long long* __restrict__ state) {
    const int b = blockIdx.x;
    const int t = threadIdx.x;
    const int lane = t & 63, wave = t >> 6;

    __shared__ int wsum[BLOCK / 64], woff[BLOCK / 64], btotal;
    __shared__ long long sBase;
    __shared__ float vals[TILE2];

    for (int gen = 0; gen < GENS; ++gen) {
        const int tile = b + gen * GRID;

        // ---- load idx tile (nontemporal: read-once, don't evict the slice) ----
        const vint4* p = (const vint4*)(idx + (size_t)tile * TILE2 + (size_t)t * EPT2);
        int v[EPT2];
#pragma unroll
        for (int j = 0; j < EPT2 / 4; ++j) {
            vint4 q = __builtin_nontemporal_load(p + j);
            v[4 * j + 0] = q.x; v[4 * j + 1] = q.y;
            v[4 * j + 2] = q.z; v[4 * j + 3] = q.w;
        }
        int cnt = 0;
#pragma unroll
        for (int j = 0; j < EPT2; ++j) cnt += (v[j] >= 0);

        // ---- block exclusive scan of per-thread counts ----
        int x = cnt;
#pragma unroll
        for (int d = 1; d < 64; d <<= 1) {
            int y = __shfl_up(x, d);
            if (lane >= d) x += y;
        }
        if (lane == 63) wsum[wave] = x;
        __syncthreads();
        if (t == 0) {
            int s = 0;
#pragma unroll
            for (int w = 0; w < BLOCK / 64; ++w) { woff[w] = s; s += wsum[w]; }
            btotal = s;
            if (tile == 0) {
                // flag 2 = PREFIX (inclusive), value in bits [2..]
                __hip_atomic_store(&state[0], ((unsigned long long)s << 2) | 2ULL,
                                   __ATOMIC_RELAXED, __HIP_MEMORY_SCOPE_AGENT);
                sBase = 0;
            } else {
                // flag 1 = PARTIAL -- published BEFORE the gather phase
                __hip_atomic_store(&state[tile], ((unsigned long long)s << 2) | 1ULL,
                                   __ATOMIC_RELAXED, __HIP_MEMORY_SCOPE_AGENT);
            }
        }
        __syncthreads();

        const int off0 = (x - cnt) + woff[wave];   // this thread's first LDS slot

        // ---- slice-swept batched gather -> LDS compact ----
        // Per slice: EPT2 BRANCH-FREE loads (non-matching lanes read src[0],
        // L1-hot) -> one vmcnt(0) -> conditional LDS commit. With all 2048
        // blocks resident and in-phase, the 4MB slice stays in each XCD's L2.
#pragma unroll 1
        for (int s = 0; s < SLICES; ++s) {
            float tmp[EPT2];
#pragma unroll
            for (int j = 0; j < EPT2; ++j) {
                const bool m = (int)((unsigned)v[j] >> SLICE_LG) == s;
                tmp[j] = src[m ? v[j] : 0];
            }
            asm volatile("s_waitcnt vmcnt(0)" ::: "memory");
            int o = off0;
#pragma unroll
            for (int j = 0; j < EPT2; ++j) {
                const bool acc = v[j] >= 0;
                const bool m = (int)((unsigned)v[j] >> SLICE_LG) == s;
                if (m) vals[o] = tmp[j];
                o += acc;
            }
        }

        // ---- decoupled lookback AFTER the sweep (predecessors published) ----
        if (tile > 0 && wave == 0) {
            long long excl = 0;
            int look = tile - 1;
            for (;;) {
                const int pos = look - lane;          // lane 0 = nearest predecessor
                unsigned long long s = 2ULL;          // pos<0 -> fake PREFIX(0)
                if (pos >= 0)
                    s = __hip_atomic_load(&state[pos], __ATOMIC_RELAXED,
                                          __HIP_MEMORY_SCOPE_AGENT);
                for (;;) {
                    const bool need = (pos >= 0) && ((s & 3ULL) == 0ULL);
                    if (!__any(need)) break;
                    if (need) {
                        __builtin_amdgcn_s_sleep(2);  // throttle spin traffic
                        s = __hip_atomic_load(&state[pos], __ATOMIC_RELAXED,
                                              __HIP_MEMORY_SCOPE_AGENT);
                    }
                }
                const unsigned long long ball = __ballot((s & 3ULL) == 2ULL);
                const int fp = ball ? (__ffsll((long long)ball) - 1) : 64;
                long long c = (lane <= fp) ? (long long)(s >> 2) : 0;
#pragma unroll
                for (int d = 32; d; d >>= 1) c += __shfl_down(c, d);
                excl += __shfl(c, 0);
                if (ball) break;                      // found a PREFIX -> done
                look -= 64;                           // whole window PARTIAL
            }
            if (lane == 0) {
                __hip_atomic_store(&state[tile],
                                   (((unsigned long long)(excl + btotal)) << 2) | 2ULL,
                                   __ATOMIC_RELAXED, __HIP_MEMORY_SCOPE_AGENT);
                sBase = excl;
            }
        }
        __syncthreads();

        const int tot = btotal;
        const long long base = sBase;          // global exclusive accept prefix

        // ---- data write [base, base+tot): float4 NT with alignment peel ----
        {
            const long long gbeg = base, gend = base + tot;
            const long long a0 = (gbeg + 3) & ~3LL;   // first 16B-aligned idx
            const long long a1 = gend & ~3LL;         // end of vector region
            const long long hend = a0 < gend ? a0 : gend;
            for (long long g = gbeg + t; g < hend; g += BLOCK)
                __builtin_nontemporal_store(vals[(int)(g - gbeg)], out + g);
            if (a0 < gend) {
                for (long long g = a0 + (long long)t * 4; g < a1; g += (long long)BLOCK * 4) {
                    const int l = (int)(g - gbeg);
                    vfloat4 w = { vals[l], vals[l + 1], vals[l + 2], vals[l + 3] };
                    __builtin_nontemporal_store(w, (vfloat4*)(out + g));
                }
                for (long long g = a1 + t; g < gend; g += BLOCK)
                    __builtin_nontemporal_store(vals[(int)(g - gbeg)], out + g);
            }
        }

        // ---- fused tail zero via reject-prefix identity ----
        // rejects before this tile: r = tile*TILE2 - base; this tile owes
        // rcnt = TILE2 - tot zeros at [N - r - rcnt, N - r). Union over all
        // tiles = [total, N), disjoint, never overlaps data writes.
        {
            const long long rprev = (long long)tile * TILE2 - base;
            const int rcnt = TILE2 - tot;
            const long long zbeg = (long long)N_TOTAL - rprev - rcnt;
            const long long zend = (long long)N_TOTAL - rprev;
            const long long a0 = (zbeg + 3) & ~3LL;
            const long long a1 = zend & ~3LL;
            const long long hend = a0 < zend ? a0 : zend;
            for (long long g = zbeg + t; g < hend; g += BLOCK)
                __builtin_nontemporal_store(0.0f, out + g);
            if (a0 < zend) {
                const vfloat4 z = (vfloat4)(0.f);
                for (long long g = a0 + (long long)t * 4; g < a1; g += (long long)BLOCK * 4)
                    __builtin_nontemporal_store(z, (vfloat4*)(out + g));
                for (long long g = a1 + t; g < zend; g += BLOCK)
                    __builtin_nontemporal_store(0.0f, out + g);
            }
        }

        __syncthreads();   // vals/shared reused by next generation
    }
}

extern "C" void kernel_launch(void* const* d_in, const int* in_sizes, int n_in,
                              void* d_out, int out_size, void* d_ws, size_t ws_size,
                              hipStream_t stream) {
    const int*   idx = (const int*)d_in[0];     // accept_index (int32 per harness)
    const float* src = (const float*)d_in[1];   // out_cache_loc
    float*       out = (float*)d_out;

    unsigned long long* state = (unsigned long long*)d_ws;  // NB2 x u64 = 32 KB

    k_init   <<<NB2 / 256, 256, 0, stream>>>(state);
    k_compact<<<GRID, BLOCK, 0, stream>>>(idx, src, out, state);
}